// Round 7
// baseline (184.332 us; speedup 1.0000x reference)
//
#include <hip/hip_runtime.h>

// ConvCaps (Matrix Capsules w/ EM routing), MI355X fp32 implementation.
// One block per output position (b, oi, oj): 784 blocks x 512 threads.
//
// v6 (resubmit — round-6 bench hit GPUAcquisitionTimeout, no data):
// p-split TLP. v5 post-mortem: v4 was GRID-limited (784 blocks x 4 waves
// = 3 waves/SIMD; VGPR/LDS allowed more) and per-wave serial chains left
// VALUBusy at 45%. v5's ILP attempt raised VGPR past the 128 granule and
// regressed. v6 doubles resident waves at constant grid: 512-thread blocks,
// lane bit 5 = ph selects rows {0,1}/{2,3} of the 4x4 vote matrix. Per-thread
// state halves (T1/T2/hi/hm/mu -> 8 elems, ~41 long-lived VGPRs); the only
// new cost is one __shfl_xor(s,32) partner-combine per chunk (full-p
// quadratic sum) and once-per-pass combines of logsum/K. v4's half-combine
// of T over lane bit 5 is REMOVED (that bit is now p, not n); all 64 lanes
// write their p-half to sRed (8 wave rows). Softmax over 32 classes stays
// intra-32-lane-group: 4 DPP row_ror + 1 ds_swizzle(xor16), as v4.
// __launch_bounds__(512,6): 3 blocks/CU (LDS 51KB x3 = 154KB), 6 waves/SIMD.

namespace {

constexpr int OHW  = 14;
constexpr int NPOS = 4 * OHW * OHW;     // 784
constexpr int NN   = 144;               // K*K*B = 3*3*16
constexpr int CC   = 32;
constexpr float LAMB  = 0.01f;
constexpr float EPSF  = 1e-6f;
constexpr float LN2PI = 1.8378770664093453f;
constexpr int NSUB = 8;                 // n-slices: one per wave
constexpr int NCH  = NN / NSUB;         // 18 chunks per pass
constexpr int RST  = 36;                // sRed/sStat row stride (floats)

// DPP cross-lane move within rows of 16 (VALU, no DS). CTRL: row_ror:N = 0x120|N.
template <int CTRL>
__device__ __forceinline__ float dpp_mov(float x) {
  union { float f; int i; } u, r;
  u.f = x;
  r.i = __builtin_amdgcn_update_dpp(0, u.i, CTRL, 0xF, 0xF, true);
  return r.f;
}

// lane ^ 16 within each 32-lane group (one DS op). BitMode offset = (16<<10)|0x1F.
__device__ __forceinline__ float swz_xor16(float x) {
  union { float f; int i; } u, r;
  u.f = x;
  r.i = __builtin_amdgcn_ds_swizzle(u.i, 0x401F);
  return r.f;
}

// half mat44: rows i0=2*ph, 2*ph+1 of P(4x4) x W(4x4) -> v[8]
__device__ __forceinline__ void mat44h(const float4 pr[2], const float4 wr[4], float v[8]) {
  #pragma unroll
  for (int i = 0; i < 2; ++i) {
    v[4*i+0] = fmaf(pr[i].x, wr[0].x, fmaf(pr[i].y, wr[1].x, fmaf(pr[i].z, wr[2].x, pr[i].w * wr[3].x)));
    v[4*i+1] = fmaf(pr[i].x, wr[0].y, fmaf(pr[i].y, wr[1].y, fmaf(pr[i].z, wr[2].y, pr[i].w * wr[3].y)));
    v[4*i+2] = fmaf(pr[i].x, wr[0].z, fmaf(pr[i].y, wr[1].z, fmaf(pr[i].z, wr[2].z, pr[i].w * wr[3].z)));
    v[4*i+3] = fmaf(pr[i].x, wr[0].w, fmaf(pr[i].y, wr[1].w, fmaf(pr[i].z, wr[2].w, pr[i].w * wr[3].w)));
  }
}

__device__ __forceinline__ void loadw(float4 wr[4], const float* __restrict__ w, int n, int c) {
  const float4* W = (const float4*)(w + n * 512 + c * 16);
  wr[0] = W[0]; wr[1] = W[1]; wr[2] = W[2]; wr[3] = W[3];
}

__global__ __launch_bounds__(512, 6)
void convcaps_em(const float* __restrict__ x,
                 const float* __restrict__ a,
                 const float* __restrict__ w,        // (144, 32, 4, 4)
                 const float* __restrict__ beta_u,   // (32,1)
                 const float* __restrict__ beta_a,   // (32,1)
                 const int*   __restrict__ iters_p,
                 float* __restrict__ out_mu,         // (4,14,14,32,16)
                 float* __restrict__ out_a)          // (4,14,14,32,1)
{
  __shared__ __align__(16) float sP[NN * 16];        // pose patch (broadcast reads)
  __shared__ float sA[NN];                           // input activations
  __shared__ __align__(16) float sRed[NSUB][CC][RST];// per-wave partials: [0..15]=T1 [16..31]=T2 [32]=T0
  __shared__ __align__(16) float sStat[CC][RST];     // reduced stats per class

  const int tid = threadIdx.x;
  const int pos = blockIdx.x;
  const int b   = pos / (OHW * OHW);
  const int rem = pos - b * (OHW * OHW);
  const int oi  = rem / OHW;
  const int oj  = rem - oi * OHW;

  int iters = iters_p[0];
  iters = (iters < 1) ? 1 : (iters > 16 ? 16 : iters);

  // ---- stage pose patch + activations ----
  // i = t*256 + r, t = kh*3+kw; x[b, oi+kh, oj+kw, :, :] is 256 contiguous floats
  for (int i = tid; i < NN * 16; i += 512) {
    const int t = i >> 8, r = i & 255;
    const int kh = t / 3, kw = t % 3;
    sP[i] = x[(((b * 16 + oi + kh) * 16) + (oj + kw)) * 256 + r];
  }
  if (tid < NN) {
    const int kh = tid / 48, kw = (tid >> 4) % 3, bc = tid & 15;
    sA[tid] = a[(((b * 16 + oi + kh) * 16) + (oj + kw)) * 16 + bc];
  }
  __syncthreads();

  // thread map: c in lane bits 0..4 (softmax group = 32-lane half-wave),
  // ph = lane bit 5 (p-half: vote rows 2ph..2ph+1), sub = wave id (n-slice).
  const int lane = tid & 63;
  const int wv   = tid >> 6;              // 0..7
  const int c    = lane & 31;
  const int ph   = lane >> 5;             // 0..1
  const int sub  = wv;                    // 0..7
  const float bu16 = 16.0f * beta_u[c];
  const float ba   = beta_a[c];

  float mu[8], hi[8], hm[8];
  float kcp = 0.f, aout = 0.f;

  for (int it = 0; it < iters; ++it) {
    float T0 = 0.f, T1[8], T2[8];
    #pragma unroll
    for (int p = 0; p < 8; ++p) { T1[p] = 0.f; T2[p] = 0.f; }

    float4 wr[4];
    loadw(wr, w, sub, c);

    if (it == 0) {
      // ---- M0: r ~ a_in (unnormalized), no softmax ----
      #pragma unroll 1
      for (int ch = 0; ch < NCH; ++ch) {
        const int n = sub + NSUB * ch;
        const float4* Pp = (const float4*)(sP + n * 16 + ph * 8);
        const float4 pr[2] = {Pp[0], Pp[1]};
        float v[8];
        mat44h(pr, wr, v);
        if (ch < NCH - 1) loadw(wr, w, n + NSUB, c);
        const float rn = sA[n];
        T0 += rn;
        #pragma unroll
        for (int p = 0; p < 8; ++p) {
          const float rv = rn * v[p];
          T1[p] += rv;
          T2[p] = fmaf(rv, v[p], T2[p]);
        }
      }
    } else {
      // ---- fused E+M: softmax over classes, DPP + one swizzle per chain ----
      #pragma unroll 1
      for (int ch = 0; ch < NCH; ++ch) {
        const int n = sub + NSUB * ch;
        const float4* Pp = (const float4*)(sP + n * 16 + ph * 8);
        const float4 pr[2] = {Pp[0], Pp[1]};
        float v[8];
        mat44h(pr, wr, v);
        if (ch < NCH - 1) loadw(wr, w, n + NSUB, c);
        // s_half = sum over this thread's 8 p of hi*v^2 + hm*v
        float s0 = 0.f, s1 = 0.f;
        #pragma unroll
        for (int p = 0; p < 4; ++p) {
          s0 = fmaf(fmaf(hi[p],     v[p],     hm[p]),     v[p],     s0);
          s1 = fmaf(fmaf(hi[p + 4], v[p + 4], hm[p + 4]), v[p + 4], s1);
        }
        float s = s0 + s1;
        s += __shfl_xor(s, 32);            // partner p-half: full 16-p sum
        const float xv = kcp - s;
        // 32-lane allreduce max: 4 DPP row_ror (within-16) + 1 swizzle (xor16)
        float m = xv;
        m = fmaxf(m, dpp_mov<0x128>(m));   // ror 8
        m = fmaxf(m, dpp_mov<0x124>(m));   // ror 4
        m = fmaxf(m, dpp_mov<0x122>(m));   // ror 2
        m = fmaxf(m, dpp_mov<0x121>(m));   // ror 1
        m = fmaxf(m, swz_xor16(m));
        const float e = __expf(xv - m);
        float z = e;
        z += dpp_mov<0x128>(z);
        z += dpp_mov<0x124>(z);
        z += dpp_mov<0x122>(z);
        z += dpp_mov<0x121>(z);
        z += swz_xor16(z);
        const float rn = sA[n] * e * __builtin_amdgcn_rcpf(z);
        T0 += rn;
        #pragma unroll
        for (int p = 0; p < 8; ++p) {
          const float rv = rn * v[p];
          T1[p] += rv;
          T2[p] = fmaf(rv, v[p], T2[p]);
        }
      }
    }

    // ---- once-per-pass cross-wave reduce (2 barriers) ----
    // every lane writes its p-half; T0 only from ph==0 (both halves hold it)
    {
      float4* d1 = (float4*)(&sRed[wv][c][ph * 8]);
      d1[0] = make_float4(T1[0], T1[1], T1[2], T1[3]);
      d1[1] = make_float4(T1[4], T1[5], T1[6], T1[7]);
      float4* d2 = (float4*)(&sRed[wv][c][16 + ph * 8]);
      d2[0] = make_float4(T2[0], T2[1], T2[2], T2[3]);
      d2[1] = make_float4(T2[4], T2[5], T2[6], T2[7]);
      if (ph == 0) sRed[wv][c][32] = T0;
    }
    __syncthreads();
    {
      // 512 threads x 2 slots cover the 32c x 32slot grid; tid<32 do T0.
      const int c2 = tid & 31;
      const int s2 = tid >> 5;            // 0..15
      float q0 = 0.f, q1 = 0.f;
      #pragma unroll
      for (int wq = 0; wq < NSUB; ++wq) {
        q0 += sRed[wq][c2][s2];
        q1 += sRed[wq][c2][s2 + 16];
      }
      sStat[c2][s2]      = q0;
      sStat[c2][s2 + 16] = q1;
      if (tid < 32) {
        float q = 0.f;
        #pragma unroll
        for (int wq = 0; wq < NSUB; ++wq) q += sRed[wq][tid][32];
        sStat[tid][32] = q;
      }
    }
    __syncthreads();

    // ---- per-class stats: each thread computes its p-half; combine scalars ----
    const float4* R1 = (const float4*)(&sStat[c][ph * 8]);
    const float4 u1a = R1[0], u1b = R1[1];
    const float4* R2 = (const float4*)(&sStat[c][16 + ph * 8]);
    const float4 u2a = R2[0], u2b = R2[1];
    const float U0 = sStat[c][32];
    const float U1[8] = {u1a.x,u1a.y,u1a.z,u1a.w, u1b.x,u1b.y,u1b.z,u1b.w};
    const float U2[8] = {u2a.x,u2a.y,u2a.z,u2a.w, u2b.x,u2b.y,u2b.z,u2b.w};

    // it==0: coeff = a/(sum a + 32*EPS), r_sum = U0/32; else coeff = r/(T0+EPS), r_sum = T0
    const float inv  = 1.0f / (U0 + ((it == 0) ? (CC * EPSF) : EPSF));
    const float rsum = (it == 0) ? U0 * (1.0f / CC) : U0;
    float logsum = 0.f;
    #pragma unroll
    for (int p = 0; p < 8; ++p) {
      const float m = U1[p] * inv;
      mu[p] = m;
      float sig = fmaf(m, fmaf(m, U0, -2.0f * U1[p]), U2[p]) * inv + EPSF;
      sig = fmaxf(sig, 1e-12f);
      logsum += __logf(sig);
      hi[p] = 0.5f / sig;
    }
    logsum += __shfl_xor(logsum, 32);      // full 16-p logsum
    const float cost = rsum * (bu16 + 0.5f * logsum);
    aout = 1.0f / (1.0f + __expf(-LAMB * (ba - cost)));

    if (it < iters - 1) {
      float K = 0.f;
      #pragma unroll
      for (int p = 0; p < 8; ++p) {
        hm[p] = -2.0f * hi[p] * mu[p];
        K = fmaf(hi[p] * mu[p], mu[p], K);
      }
      K += __shfl_xor(K, 32);              // full 16-p constant
      kcp = __logf(aout + EPSF) - 0.5f * logsum - 8.0f * LN2PI - K;
    }
  }

  // ---- epilogue: wave 0 holds every (class, p-half) once ----
  if (wv == 0) {
    float4* om = (float4*)(out_mu + (size_t)pos * 512 + c * 16 + ph * 8);
    om[0] = make_float4(mu[0], mu[1], mu[2], mu[3]);
    om[1] = make_float4(mu[4], mu[5], mu[6], mu[7]);
    if (ph == 0) out_a[pos * CC + c] = aout;
  }
}

} // namespace

extern "C" void kernel_launch(void* const* d_in, const int* in_sizes, int n_in,
                              void* d_out, int out_size, void* d_ws, size_t ws_size,
                              hipStream_t stream) {
  const float* x  = (const float*)d_in[0];
  const float* a  = (const float*)d_in[1];
  const float* w  = (const float*)d_in[2];
  const float* bu = (const float*)d_in[3];
  const float* ba = (const float*)d_in[4];
  const int* iters = (const int*)d_in[5];

  float* out_mu = (float*)d_out;                       // 4*14*14*32*16 = 401408
  float* out_a  = out_mu + (size_t)NPOS * CC * 16;     // + 4*14*14*32  =  25088

  convcaps_em<<<NPOS, 512, 0, stream>>>(x, a, w, bu, ba, iters, out_mu, out_a);
}

// Round 8
// 135.093 us; speedup vs baseline: 1.3645x; 1.3645x over previous
//
#include <hip/hip_runtime.h>

// ConvCaps (Matrix Capsules w/ EM routing), MI355X fp32 implementation.
// One block per output position (b, oi, oj): 784 blocks x 512 threads.
//
// v7 = v6 with the launch-bounds occupancy demand removed. v6's
// __launch_bounds__(512,6) capped VGPRs at ~85 and the allocator landed at
// 40 — below the ~60-70 live floats/thread — spilling T1/T2/hi/hm/mu to
// scratch: FETCH 4.3->49.5MB, WRITE 1.7->75.3MB, 131.6us. Spills, not
// occupancy, dominated. Plain __launch_bounds__(512) lets the allocator
// size naturally (~64-85 VGPR expected): no spill, and LDS (51.7KB) still
// permits 3 blocks/CU (6 waves/SIMD) when VGPR <= 85.
// Structure unchanged from v6: p-split TLP (lane bit 5 = vote-row half),
// per-thread state halved, one extra shfl_xor(s,32) per fused chunk,
// DPP+swizzle class softmax, once-per-pass cross-wave LDS reduce.

namespace {

constexpr int OHW  = 14;
constexpr int NPOS = 4 * OHW * OHW;     // 784
constexpr int NN   = 144;               // K*K*B = 3*3*16
constexpr int CC   = 32;
constexpr float LAMB  = 0.01f;
constexpr float EPSF  = 1e-6f;
constexpr float LN2PI = 1.8378770664093453f;
constexpr int NSUB = 8;                 // n-slices: one per wave
constexpr int NCH  = NN / NSUB;         // 18 chunks per pass
constexpr int RST  = 36;                // sRed/sStat row stride (floats)

// DPP cross-lane move within rows of 16 (VALU, no DS). CTRL: row_ror:N = 0x120|N.
template <int CTRL>
__device__ __forceinline__ float dpp_mov(float x) {
  union { float f; int i; } u, r;
  u.f = x;
  r.i = __builtin_amdgcn_update_dpp(0, u.i, CTRL, 0xF, 0xF, true);
  return r.f;
}

// lane ^ 16 within each 32-lane group (one DS op). BitMode offset = (16<<10)|0x1F.
__device__ __forceinline__ float swz_xor16(float x) {
  union { float f; int i; } u, r;
  u.f = x;
  r.i = __builtin_amdgcn_ds_swizzle(u.i, 0x401F);
  return r.f;
}

// half mat44: rows i0=2*ph, 2*ph+1 of P(4x4) x W(4x4) -> v[8]
__device__ __forceinline__ void mat44h(const float4 pr[2], const float4 wr[4], float v[8]) {
  #pragma unroll
  for (int i = 0; i < 2; ++i) {
    v[4*i+0] = fmaf(pr[i].x, wr[0].x, fmaf(pr[i].y, wr[1].x, fmaf(pr[i].z, wr[2].x, pr[i].w * wr[3].x)));
    v[4*i+1] = fmaf(pr[i].x, wr[0].y, fmaf(pr[i].y, wr[1].y, fmaf(pr[i].z, wr[2].y, pr[i].w * wr[3].y)));
    v[4*i+2] = fmaf(pr[i].x, wr[0].z, fmaf(pr[i].y, wr[1].z, fmaf(pr[i].z, wr[2].z, pr[i].w * wr[3].z)));
    v[4*i+3] = fmaf(pr[i].x, wr[0].w, fmaf(pr[i].y, wr[1].w, fmaf(pr[i].z, wr[2].w, pr[i].w * wr[3].w)));
  }
}

__device__ __forceinline__ void loadw(float4 wr[4], const float* __restrict__ w, int n, int c) {
  const float4* W = (const float4*)(w + n * 512 + c * 16);
  wr[0] = W[0]; wr[1] = W[1]; wr[2] = W[2]; wr[3] = W[3];
}

__global__ __launch_bounds__(512)
void convcaps_em(const float* __restrict__ x,
                 const float* __restrict__ a,
                 const float* __restrict__ w,        // (144, 32, 4, 4)
                 const float* __restrict__ beta_u,   // (32,1)
                 const float* __restrict__ beta_a,   // (32,1)
                 const int*   __restrict__ iters_p,
                 float* __restrict__ out_mu,         // (4,14,14,32,16)
                 float* __restrict__ out_a)          // (4,14,14,32,1)
{
  __shared__ __align__(16) float sP[NN * 16];        // pose patch (broadcast reads)
  __shared__ float sA[NN];                           // input activations
  __shared__ __align__(16) float sRed[NSUB][CC][RST];// per-wave partials: [0..15]=T1 [16..31]=T2 [32]=T0
  __shared__ __align__(16) float sStat[CC][RST];     // reduced stats per class

  const int tid = threadIdx.x;
  const int pos = blockIdx.x;
  const int b   = pos / (OHW * OHW);
  const int rem = pos - b * (OHW * OHW);
  const int oi  = rem / OHW;
  const int oj  = rem - oi * OHW;

  int iters = iters_p[0];
  iters = (iters < 1) ? 1 : (iters > 16 ? 16 : iters);

  // ---- stage pose patch + activations ----
  // i = t*256 + r, t = kh*3+kw; x[b, oi+kh, oj+kw, :, :] is 256 contiguous floats
  for (int i = tid; i < NN * 16; i += 512) {
    const int t = i >> 8, r = i & 255;
    const int kh = t / 3, kw = t % 3;
    sP[i] = x[(((b * 16 + oi + kh) * 16) + (oj + kw)) * 256 + r];
  }
  if (tid < NN) {
    const int kh = tid / 48, kw = (tid >> 4) % 3, bc = tid & 15;
    sA[tid] = a[(((b * 16 + oi + kh) * 16) + (oj + kw)) * 16 + bc];
  }
  __syncthreads();

  // thread map: c in lane bits 0..4 (softmax group = 32-lane half-wave),
  // ph = lane bit 5 (p-half: vote rows 2ph..2ph+1), sub = wave id (n-slice).
  const int lane = tid & 63;
  const int wv   = tid >> 6;              // 0..7
  const int c    = lane & 31;
  const int ph   = lane >> 5;             // 0..1
  const int sub  = wv;                    // 0..7
  const float bu16 = 16.0f * beta_u[c];
  const float ba   = beta_a[c];

  float mu[8], hi[8], hm[8];
  float kcp = 0.f, aout = 0.f;

  for (int it = 0; it < iters; ++it) {
    float T0 = 0.f, T1[8], T2[8];
    #pragma unroll
    for (int p = 0; p < 8; ++p) { T1[p] = 0.f; T2[p] = 0.f; }

    float4 wr[4];
    loadw(wr, w, sub, c);

    if (it == 0) {
      // ---- M0: r ~ a_in (unnormalized), no softmax ----
      #pragma unroll 1
      for (int ch = 0; ch < NCH; ++ch) {
        const int n = sub + NSUB * ch;
        const float4* Pp = (const float4*)(sP + n * 16 + ph * 8);
        const float4 pr[2] = {Pp[0], Pp[1]};
        float v[8];
        mat44h(pr, wr, v);
        if (ch < NCH - 1) loadw(wr, w, n + NSUB, c);
        const float rn = sA[n];
        T0 += rn;
        #pragma unroll
        for (int p = 0; p < 8; ++p) {
          const float rv = rn * v[p];
          T1[p] += rv;
          T2[p] = fmaf(rv, v[p], T2[p]);
        }
      }
    } else {
      // ---- fused E+M: softmax over classes, DPP + one swizzle per chain ----
      #pragma unroll 1
      for (int ch = 0; ch < NCH; ++ch) {
        const int n = sub + NSUB * ch;
        const float4* Pp = (const float4*)(sP + n * 16 + ph * 8);
        const float4 pr[2] = {Pp[0], Pp[1]};
        float v[8];
        mat44h(pr, wr, v);
        if (ch < NCH - 1) loadw(wr, w, n + NSUB, c);
        // s_half = sum over this thread's 8 p of hi*v^2 + hm*v
        float s0 = 0.f, s1 = 0.f;
        #pragma unroll
        for (int p = 0; p < 4; ++p) {
          s0 = fmaf(fmaf(hi[p],     v[p],     hm[p]),     v[p],     s0);
          s1 = fmaf(fmaf(hi[p + 4], v[p + 4], hm[p + 4]), v[p + 4], s1);
        }
        float s = s0 + s1;
        s += __shfl_xor(s, 32);            // partner p-half: full 16-p sum
        const float xv = kcp - s;
        // 32-lane allreduce max: 4 DPP row_ror (within-16) + 1 swizzle (xor16)
        float m = xv;
        m = fmaxf(m, dpp_mov<0x128>(m));   // ror 8
        m = fmaxf(m, dpp_mov<0x124>(m));   // ror 4
        m = fmaxf(m, dpp_mov<0x122>(m));   // ror 2
        m = fmaxf(m, dpp_mov<0x121>(m));   // ror 1
        m = fmaxf(m, swz_xor16(m));
        const float e = __expf(xv - m);
        float z = e;
        z += dpp_mov<0x128>(z);
        z += dpp_mov<0x124>(z);
        z += dpp_mov<0x122>(z);
        z += dpp_mov<0x121>(z);
        z += swz_xor16(z);
        const float rn = sA[n] * e * __builtin_amdgcn_rcpf(z);
        T0 += rn;
        #pragma unroll
        for (int p = 0; p < 8; ++p) {
          const float rv = rn * v[p];
          T1[p] += rv;
          T2[p] = fmaf(rv, v[p], T2[p]);
        }
      }
    }

    // ---- once-per-pass cross-wave reduce (2 barriers) ----
    // every lane writes its p-half; T0 only from ph==0 (both halves hold it)
    {
      float4* d1 = (float4*)(&sRed[wv][c][ph * 8]);
      d1[0] = make_float4(T1[0], T1[1], T1[2], T1[3]);
      d1[1] = make_float4(T1[4], T1[5], T1[6], T1[7]);
      float4* d2 = (float4*)(&sRed[wv][c][16 + ph * 8]);
      d2[0] = make_float4(T2[0], T2[1], T2[2], T2[3]);
      d2[1] = make_float4(T2[4], T2[5], T2[6], T2[7]);
      if (ph == 0) sRed[wv][c][32] = T0;
    }
    __syncthreads();
    {
      // 512 threads x 2 slots cover the 32c x 32slot grid; tid<32 do T0.
      const int c2 = tid & 31;
      const int s2 = tid >> 5;            // 0..15
      float q0 = 0.f, q1 = 0.f;
      #pragma unroll
      for (int wq = 0; wq < NSUB; ++wq) {
        q0 += sRed[wq][c2][s2];
        q1 += sRed[wq][c2][s2 + 16];
      }
      sStat[c2][s2]      = q0;
      sStat[c2][s2 + 16] = q1;
      if (tid < 32) {
        float q = 0.f;
        #pragma unroll
        for (int wq = 0; wq < NSUB; ++wq) q += sRed[wq][tid][32];
        sStat[tid][32] = q;
      }
    }
    __syncthreads();

    // ---- per-class stats: each thread computes its p-half; combine scalars ----
    const float4* R1 = (const float4*)(&sStat[c][ph * 8]);
    const float4 u1a = R1[0], u1b = R1[1];
    const float4* R2 = (const float4*)(&sStat[c][16 + ph * 8]);
    const float4 u2a = R2[0], u2b = R2[1];
    const float U0 = sStat[c][32];
    const float U1[8] = {u1a.x,u1a.y,u1a.z,u1a.w, u1b.x,u1b.y,u1b.z,u1b.w};
    const float U2[8] = {u2a.x,u2a.y,u2a.z,u2a.w, u2b.x,u2b.y,u2b.z,u2b.w};

    // it==0: coeff = a/(sum a + 32*EPS), r_sum = U0/32; else coeff = r/(T0+EPS), r_sum = T0
    const float inv  = 1.0f / (U0 + ((it == 0) ? (CC * EPSF) : EPSF));
    const float rsum = (it == 0) ? U0 * (1.0f / CC) : U0;
    float logsum = 0.f;
    #pragma unroll
    for (int p = 0; p < 8; ++p) {
      const float m = U1[p] * inv;
      mu[p] = m;
      float sig = fmaf(m, fmaf(m, U0, -2.0f * U1[p]), U2[p]) * inv + EPSF;
      sig = fmaxf(sig, 1e-12f);
      logsum += __logf(sig);
      hi[p] = 0.5f / sig;
    }
    logsum += __shfl_xor(logsum, 32);      // full 16-p logsum
    const float cost = rsum * (bu16 + 0.5f * logsum);
    aout = 1.0f / (1.0f + __expf(-LAMB * (ba - cost)));

    if (it < iters - 1) {
      float K = 0.f;
      #pragma unroll
      for (int p = 0; p < 8; ++p) {
        hm[p] = -2.0f * hi[p] * mu[p];
        K = fmaf(hi[p] * mu[p], mu[p], K);
      }
      K += __shfl_xor(K, 32);              // full 16-p constant
      kcp = __logf(aout + EPSF) - 0.5f * logsum - 8.0f * LN2PI - K;
    }
  }

  // ---- epilogue: wave 0 holds every (class, p-half) once ----
  if (wv == 0) {
    float4* om = (float4*)(out_mu + (size_t)pos * 512 + c * 16 + ph * 8);
    om[0] = make_float4(mu[0], mu[1], mu[2], mu[3]);
    om[1] = make_float4(mu[4], mu[5], mu[6], mu[7]);
    if (ph == 0) out_a[pos * CC + c] = aout;
  }
}

} // namespace

extern "C" void kernel_launch(void* const* d_in, const int* in_sizes, int n_in,
                              void* d_out, int out_size, void* d_ws, size_t ws_size,
                              hipStream_t stream) {
  const float* x  = (const float*)d_in[0];
  const float* a  = (const float*)d_in[1];
  const float* w  = (const float*)d_in[2];
  const float* bu = (const float*)d_in[3];
  const float* ba = (const float*)d_in[4];
  const int* iters = (const int*)d_in[5];

  float* out_mu = (float*)d_out;                       // 4*14*14*32*16 = 401408
  float* out_a  = out_mu + (size_t)NPOS * CC * 16;     // + 4*14*14*32  =  25088

  convcaps_em<<<NPOS, 512, 0, stream>>>(x, a, w, bu, ba, iters, out_mu, out_a);
}

// Round 10
// 115.804 us; speedup vs baseline: 1.5918x; 1.1666x over previous
//
#include <hip/hip_runtime.h>

// ConvCaps (Matrix Capsules w/ EM routing), MI355X fp32 implementation.
// One block per output position (b, oi, oj): 784 blocks x 256 threads.
//
// v8 (resubmit — round-9 bench hit GPUAcquisitionTimeout, no data):
// v4 (best measured: 60.4us rocprof) + per-wave chunk-phase stagger.
// v7's null showed more waves don't help (VALUBusy pinned ~45% at both 3 and
// 6 waves/SIMD): co-resident waves run the IDENTICAL chunk schedule in
// barrier-synced lockstep, so their long dependent chains (mat44 -> s-tree ->
// DPP max -> exp -> DPP sum -> rcp) and DS/VMEM phases stall simultaneously.
// Fix: wave wv starts its private 18-chunk loop at chunk (wv*5)%18 and wraps
// (offsets 0/5/10/15), decorrelating pipe demands across waves. Per-wave
// sums are order-invariant (ulp-level only). Everything else identical to v4.

namespace {

constexpr int OHW  = 14;
constexpr int NPOS = 4 * OHW * OHW;     // 784
constexpr int NN   = 144;               // K*K*B = 3*3*16
constexpr int CC   = 32;
constexpr float LAMB  = 0.01f;
constexpr float EPSF  = 1e-6f;
constexpr float LN2PI = 1.8378770664093453f;
constexpr int NSUB = 8;                 // n-slices: 4 waves x 2 halves
constexpr int NCH  = NN / NSUB;         // 18 chunks per pass
constexpr int RST  = 36;                // sRed/sStat row stride (floats)

// DPP cross-lane move within rows of 16 (VALU, no DS). CTRL: row_ror:N = 0x120|N.
template <int CTRL>
__device__ __forceinline__ float dpp_mov(float x) {
  union { float f; int i; } u, r;
  u.f = x;
  r.i = __builtin_amdgcn_update_dpp(0, u.i, CTRL, 0xF, 0xF, true);
  return r.f;
}

// lane ^ 16 within each 32-lane group (one DS op). BitMode offset = (16<<10)|0x1F.
__device__ __forceinline__ float swz_xor16(float x) {
  union { float f; int i; } u, r;
  u.f = x;
  r.i = __builtin_amdgcn_ds_swizzle(u.i, 0x401F);
  return r.f;
}

__device__ __forceinline__ void mat44(const float4 pr[4], const float4 wr[4], float v[16]) {
  #pragma unroll
  for (int i = 0; i < 4; ++i) {
    v[4*i+0] = fmaf(pr[i].x, wr[0].x, fmaf(pr[i].y, wr[1].x, fmaf(pr[i].z, wr[2].x, pr[i].w * wr[3].x)));
    v[4*i+1] = fmaf(pr[i].x, wr[0].y, fmaf(pr[i].y, wr[1].y, fmaf(pr[i].z, wr[2].y, pr[i].w * wr[3].y)));
    v[4*i+2] = fmaf(pr[i].x, wr[0].z, fmaf(pr[i].y, wr[1].z, fmaf(pr[i].z, wr[2].z, pr[i].w * wr[3].z)));
    v[4*i+3] = fmaf(pr[i].x, wr[0].w, fmaf(pr[i].y, wr[1].w, fmaf(pr[i].z, wr[2].w, pr[i].w * wr[3].w)));
  }
}

__device__ __forceinline__ void loadw(float4 wr[4], const float* __restrict__ w, int n, int c) {
  const float4* W = (const float4*)(w + n * 512 + c * 16);
  wr[0] = W[0]; wr[1] = W[1]; wr[2] = W[2]; wr[3] = W[3];
}

__global__ __launch_bounds__(256)
void convcaps_em(const float* __restrict__ x,
                 const float* __restrict__ a,
                 const float* __restrict__ w,        // (144, 32, 4, 4)
                 const float* __restrict__ beta_u,   // (32,1)
                 const float* __restrict__ beta_a,   // (32,1)
                 const int*   __restrict__ iters_p,
                 float* __restrict__ out_mu,         // (4,14,14,32,16)
                 float* __restrict__ out_a)          // (4,14,14,32,1)
{
  __shared__ __align__(16) float sP[NN * 16];        // pose patch (broadcast reads)
  __shared__ float sA[NN];                           // input activations
  __shared__ __align__(16) float sRed[4][CC][RST];   // per-wave partials: [0..15]=S1 [16..31]=S2 [32]=S0
  __shared__ __align__(16) float sStat[CC][RST];     // reduced stats per class

  const int tid = threadIdx.x;
  const int pos = blockIdx.x;
  const int b   = pos / (OHW * OHW);
  const int rem = pos - b * (OHW * OHW);
  const int oi  = rem / OHW;
  const int oj  = rem - oi * OHW;

  int iters = iters_p[0];
  iters = (iters < 1) ? 1 : (iters > 16 ? 16 : iters);

  // ---- stage pose patch + activations ----
  #pragma unroll
  for (int t = 0; t < 9; ++t) {
    const int kh = t / 3, kw = t % 3;
    sP[t * 256 + tid] = x[(((b * 16 + oi + kh) * 16) + (oj + kw)) * 256 + tid];
  }
  if (tid < NN) {
    const int kh = tid / 48, kw = (tid >> 4) % 3, bc = tid & 15;
    sA[tid] = a[(((b * 16 + oi + kh) * 16) + (oj + kw)) * 16 + bc];
  }
  __syncthreads();

  // thread map: class in lane bits 0..4; n-slice = wv*2 + (lane>>5).
  const int lane = tid & 63;
  const int wv   = tid >> 6;
  const int c    = lane & 31;
  const int half = lane >> 5;
  const int sub  = wv * 2 + half;           // 0..7
  const int off  = wv * 5;                  // chunk-phase stagger: 0,5,10,15
  const float bu16 = 16.0f * beta_u[c];
  const float ba   = beta_a[c];

  float mu[16], hi[16], hm[16];
  float kcp = 0.f, aout = 0.f;

  for (int it = 0; it < iters; ++it) {
    float T0 = 0.f, T1[16], T2[16];
    #pragma unroll
    for (int p = 0; p < 16; ++p) { T1[p] = 0.f; T2[p] = 0.f; }

    float4 wr[4];
    loadw(wr, w, sub + NSUB * off, c);      // first (staggered) chunk's weights

    if (it == 0) {
      // ---- M0: r ~ a_in (unnormalized), no softmax ----
      #pragma unroll 1
      for (int cc = 0; cc < NCH; ++cc) {
        int ch = cc + off; if (ch >= NCH) ch -= NCH;
        const int n = sub + NSUB * ch;
        const float4* Pp = (const float4*)(sP + n * 16);
        const float4 pr[4] = {Pp[0], Pp[1], Pp[2], Pp[3]};
        float v[16];
        mat44(pr, wr, v);
        if (cc < NCH - 1) {
          int chn = ch + 1; if (chn >= NCH) chn -= NCH;
          loadw(wr, w, sub + NSUB * chn, c);
        }
        const float rn = sA[n];
        T0 += rn;
        #pragma unroll
        for (int p = 0; p < 16; ++p) {
          const float rv = rn * v[p];
          T1[p] += rv;
          T2[p] = fmaf(rv, v[p], T2[p]);
        }
      }
    } else {
      // ---- fused E+M: softmax over classes, DPP + one swizzle per chain ----
      #pragma unroll 1
      for (int cc = 0; cc < NCH; ++cc) {
        int ch = cc + off; if (ch >= NCH) ch -= NCH;
        const int n = sub + NSUB * ch;
        const float4* Pp = (const float4*)(sP + n * 16);
        const float4 pr[4] = {Pp[0], Pp[1], Pp[2], Pp[3]};
        float v[16];
        mat44(pr, wr, v);
        if (cc < NCH - 1) {
          int chn = ch + 1; if (chn >= NCH) chn -= NCH;
          loadw(wr, w, sub + NSUB * chn, c);
        }
        // s = sum_p hi*(v-mu)^2 - K  (K folded into kcp), 4-way tree
        float s0 = 0.f, s1 = 0.f, s2 = 0.f, s3 = 0.f;
        #pragma unroll
        for (int p = 0; p < 4; ++p) {
          s0 = fmaf(fmaf(hi[p],      v[p],      hm[p]),      v[p],      s0);
          s1 = fmaf(fmaf(hi[p + 4],  v[p + 4],  hm[p + 4]),  v[p + 4],  s1);
          s2 = fmaf(fmaf(hi[p + 8],  v[p + 8],  hm[p + 8]),  v[p + 8],  s2);
          s3 = fmaf(fmaf(hi[p + 12], v[p + 12], hm[p + 12]), v[p + 12], s3);
        }
        const float xv = kcp - ((s0 + s1) + (s2 + s3));
        // 32-lane allreduce max: 4 DPP row_ror (within-16) + 1 swizzle (xor16)
        float m = xv;
        m = fmaxf(m, dpp_mov<0x128>(m));   // ror 8
        m = fmaxf(m, dpp_mov<0x124>(m));   // ror 4
        m = fmaxf(m, dpp_mov<0x122>(m));   // ror 2
        m = fmaxf(m, dpp_mov<0x121>(m));   // ror 1
        m = fmaxf(m, swz_xor16(m));
        const float e = __expf(xv - m);
        float z = e;
        z += dpp_mov<0x128>(z);
        z += dpp_mov<0x124>(z);
        z += dpp_mov<0x122>(z);
        z += dpp_mov<0x121>(z);
        z += swz_xor16(z);
        const float rn = sA[n] * e * __builtin_amdgcn_rcpf(z);
        T0 += rn;
        #pragma unroll
        for (int p = 0; p < 16; ++p) {
          const float rv = rn * v[p];
          T1[p] += rv;
          T2[p] = fmaf(rv, v[p], T2[p]);
        }
      }
    }

    // ---- combine the two halves of each wave ----
    T0 += __shfl_xor(T0, 32);
    #pragma unroll
    for (int p = 0; p < 16; ++p) {
      T1[p] += __shfl_xor(T1[p], 32);
      T2[p] += __shfl_xor(T2[p], 32);
    }

    // ---- once-per-pass cross-wave reduce (2 barriers) ----
    if (half == 0) {
      float4* d = (float4*)(&sRed[wv][c][0]);
      d[0] = make_float4(T1[0],  T1[1],  T1[2],  T1[3]);
      d[1] = make_float4(T1[4],  T1[5],  T1[6],  T1[7]);
      d[2] = make_float4(T1[8],  T1[9],  T1[10], T1[11]);
      d[3] = make_float4(T1[12], T1[13], T1[14], T1[15]);
      d[4] = make_float4(T2[0],  T2[1],  T2[2],  T2[3]);
      d[5] = make_float4(T2[4],  T2[5],  T2[6],  T2[7]);
      d[6] = make_float4(T2[8],  T2[9],  T2[10], T2[11]);
      d[7] = make_float4(T2[12], T2[13], T2[14], T2[15]);
      sRed[wv][c][32] = T0;
    }
    __syncthreads();
    {
      // 256 threads x 4 slots cover the 32x32 S1/S2 grid; lanes<32 do S0.
      const int c2 = tid & 31;
      const int s2 = tid >> 5;            // 0..7
      const float q0 = sRed[0][c2][s2]      + sRed[1][c2][s2]      + sRed[2][c2][s2]      + sRed[3][c2][s2];
      const float q1 = sRed[0][c2][s2 + 8]  + sRed[1][c2][s2 + 8]  + sRed[2][c2][s2 + 8]  + sRed[3][c2][s2 + 8];
      const float q2 = sRed[0][c2][s2 + 16] + sRed[1][c2][s2 + 16] + sRed[2][c2][s2 + 16] + sRed[3][c2][s2 + 16];
      const float q3 = sRed[0][c2][s2 + 24] + sRed[1][c2][s2 + 24] + sRed[2][c2][s2 + 24] + sRed[3][c2][s2 + 24];
      sStat[c2][s2]      = q0;
      sStat[c2][s2 + 8]  = q1;
      sStat[c2][s2 + 16] = q2;
      sStat[c2][s2 + 24] = q3;
      if (tid < 32)
        sStat[tid][32] = sRed[0][tid][32] + sRed[1][tid][32] + sRed[2][tid][32] + sRed[3][tid][32];
    }
    __syncthreads();

    // ---- per-class stats (redundant across the 8 threads sharing c) ----
    const float4* R = (const float4*)(&sStat[c][0]);
    const float4 u1a = R[0], u1b = R[1], u1c = R[2], u1d = R[3];
    const float4 u2a = R[4], u2b = R[5], u2c = R[6], u2d = R[7];
    const float U0 = sStat[c][32];
    float U1[16] = {u1a.x,u1a.y,u1a.z,u1a.w, u1b.x,u1b.y,u1b.z,u1b.w,
                    u1c.x,u1c.y,u1c.z,u1c.w, u1d.x,u1d.y,u1d.z,u1d.w};
    float U2[16] = {u2a.x,u2a.y,u2a.z,u2a.w, u2b.x,u2b.y,u2b.z,u2b.w,
                    u2c.x,u2c.y,u2c.z,u2c.w, u2d.x,u2d.y,u2d.z,u2d.w};

    // it==0: coeff = a/(sum a + 32*EPS), r_sum = U0/32; else coeff = r/(T0+EPS), r_sum = T0
    const float inv  = 1.0f / (U0 + ((it == 0) ? (CC * EPSF) : EPSF));
    const float rsum = (it == 0) ? U0 * (1.0f / CC) : U0;
    float logsum = 0.f;
    #pragma unroll
    for (int p = 0; p < 16; ++p) {
      const float m = U1[p] * inv;
      mu[p] = m;
      float sig = fmaf(m, fmaf(m, U0, -2.0f * U1[p]), U2[p]) * inv + EPSF;  // sum r(v-mu)^2 * inv + eps
      sig = fmaxf(sig, 1e-12f);
      logsum += __logf(sig);
      hi[p] = 0.5f / sig;
    }
    const float cost = rsum * (bu16 + 0.5f * logsum);
    aout = 1.0f / (1.0f + __expf(-LAMB * (ba - cost)));

    if (it < iters - 1) {
      float K = 0.f;
      #pragma unroll
      for (int p = 0; p < 16; ++p) {
        hm[p] = -2.0f * hi[p] * mu[p];
        K = fmaf(hi[p] * mu[p], mu[p], K);
      }
      kcp = __logf(aout + EPSF) - 0.5f * logsum - 8.0f * LN2PI - K;
    }
  }

  // ---- epilogue: wave 0, half 0 holds every class once ----
  if (tid < 32) {
    float4* om = (float4*)(out_mu + (size_t)pos * 512 + c * 16);
    om[0] = make_float4(mu[0],  mu[1],  mu[2],  mu[3]);
    om[1] = make_float4(mu[4],  mu[5],  mu[6],  mu[7]);
    om[2] = make_float4(mu[8],  mu[9],  mu[10], mu[11]);
    om[3] = make_float4(mu[12], mu[13], mu[14], mu[15]);
    out_a[pos * CC + c] = aout;
  }
}

} // namespace

extern "C" void kernel_launch(void* const* d_in, const int* in_sizes, int n_in,
                              void* d_out, int out_size, void* d_ws, size_t ws_size,
                              hipStream_t stream) {
  const float* x  = (const float*)d_in[0];
  const float* a  = (const float*)d_in[1];
  const float* w  = (const float*)d_in[2];
  const float* bu = (const float*)d_in[3];
  const float* ba = (const float*)d_in[4];
  const int* iters = (const int*)d_in[5];

  float* out_mu = (float*)d_out;                       // 4*14*14*32*16 = 401408
  float* out_a  = out_mu + (size_t)NPOS * CC * 16;     // + 4*14*14*32  =  25088

  convcaps_em<<<NPOS, 256, 0, stream>>>(x, a, w, bu, ba, iters, out_mu, out_a);
}